// Round 5
// baseline (398.252 us; speedup 1.0000x reference)
//
#include <hip/hip_runtime.h>
#include <hip/hip_bf16.h>

#define H 8
#define DM 512
#define DK 64
#define LSEQ 4096
#define NB 2
#define NSPLIT 2
#define KSPAN (LSEQ / NSPLIT)   // keys per split = 2048
#define NIT (KSPAN / 64)        // 32 k-tiles per block

// 0.125 (1/sqrt(DK)) * log2(e): folded into Q so softmax uses exp2 directly
#define QSCALE 0.18033688011112042f

typedef float f32x4 __attribute__((ext_vector_type(4)));
typedef __bf16 bf16x8 __attribute__((ext_vector_type(8)));
typedef __bf16 bf16x2 __attribute__((ext_vector_type(2)));
typedef unsigned short u16;

__device__ __forceinline__ u16 f2bf(float f) {
    union { float f; unsigned u; } v{f};
    return (u16)((v.u + 0x8000u) >> 16);
}

// pack two fp32 -> packed bf16 pair (low = a, high = b)
__device__ __forceinline__ unsigned pkbf(float a, float b) {
#if __has_builtin(__builtin_amdgcn_cvt_pk_bf16_f32)
    union { bf16x2 v; unsigned u; } x;
    x.v = __builtin_amdgcn_cvt_pk_bf16_f32(a, b);
    return x.u;
#else
    union { float f; unsigned u; } x{a}, y{b};
    return ((x.u + 0x8000u) >> 16) | ((y.u + 0x8000u) & 0xffff0000u);
#endif
}

__device__ __forceinline__ ushort4 cvt4(float4 a) {
    union { ushort4 s; uint2 u; } o;
    o.u.x = pkbf(a.x, a.y);
    o.u.y = pkbf(a.z, a.w);
    return o.s;
}

// unpack packed bf16 pair -> two fp32
__device__ __forceinline__ float2 ubf2(unsigned u) {
    union { float f; unsigned v; } a, b;
    a.v = u << 16;
    b.v = u & 0xffff0000u;
    return make_float2(a.f, b.f);
}

__device__ __forceinline__ float fexp2(float x) {
#if __has_builtin(__builtin_amdgcn_exp2f)
    return __builtin_amdgcn_exp2f(x);
#else
    return exp2f(x);
#endif
}

__device__ __forceinline__ f32x4 mfma32(bf16x8 a, bf16x8 b, f32x4 c) {
    return __builtin_amdgcn_mfma_f32_16x16x32_bf16(a, b, c, 0, 0, 0);
}

// ---------------------------------------------------------------------------
// QKV projection, 128x128 tile (byte-identical to round 4 — kept fixed for
// attribution of the non-flash time).
// ---------------------------------------------------------------------------
__launch_bounds__(256, 2)
__global__ void proj_qkv(const float* __restrict__ Xq, const float* __restrict__ Xk,
                         const float* __restrict__ Xv,
                         const float* __restrict__ Wq, const float* __restrict__ Wk,
                         const float* __restrict__ Wv,
                         const float* __restrict__ bq, const float* __restrict__ bk,
                         const float* __restrict__ bv,
                         u16* __restrict__ qo, u16* __restrict__ ko, u16* __restrict__ vo)
{
    const int mode = blockIdx.z;
    const float* X    = (mode == 0) ? Xq : (mode == 1) ? Xk : Xv;
    const float* W    = (mode == 0) ? Wq : (mode == 1) ? Wk : Wv;
    const float* bias = (mode == 0) ? bq : (mode == 1) ? bk : bv;
    u16* out          = (mode == 0) ? qo : (mode == 1) ? ko : vo;

    __shared__ __align__(16) u16 smem[2][128][72];
    auto As = smem[0];
    auto Bs = smem[1];

    const int tid  = threadIdx.x;
    const int wave = tid >> 6;
    const int lane = tid & 63;
    const int g    = lane >> 4;
    const int ln   = lane & 15;
    const int wr   = wave >> 1;
    const int wc   = wave & 1;

    const int m0 = blockIdx.x * 128;
    const int n0 = blockIdx.y * 128;

    f32x4 acc[4][4] = {};

    for (int kb = 0; kb < DM; kb += 64) {
        #pragma unroll
        for (int i = 0; i < 8; ++i) {
            int idx = tid + 256 * i;
            int row = idx >> 4;
            int col = (idx & 15) * 4;
            float4 a = *(const float4*)(X + (size_t)(m0 + row) * DM + kb + col);
            *(ushort4*)&As[row][col] = cvt4(a);
            float4 w = *(const float4*)(W + (size_t)(n0 + row) * DM + kb + col);
            *(ushort4*)&Bs[row][col] = cvt4(w);
        }
        __syncthreads();

        bf16x8 af[4][2], bf[4][2];
        #pragma unroll
        for (int t = 0; t < 4; ++t) {
            af[t][0] = *(const bf16x8*)&As[wr * 64 + t * 16 + ln][g * 8];
            af[t][1] = *(const bf16x8*)&As[wr * 64 + t * 16 + ln][32 + g * 8];
            bf[t][0] = *(const bf16x8*)&Bs[wc * 64 + t * 16 + ln][g * 8];
            bf[t][1] = *(const bf16x8*)&Bs[wc * 64 + t * 16 + ln][32 + g * 8];
        }
        #pragma unroll
        for (int mt = 0; mt < 4; ++mt)
            #pragma unroll
            for (int nt = 0; nt < 4; ++nt) {
                acc[mt][nt] = mfma32(af[mt][0], bf[nt][0], acc[mt][nt]);
                acc[mt][nt] = mfma32(af[mt][1], bf[nt][1], acc[mt][nt]);
            }
        __syncthreads();
    }

    if (mode != 2) {
        #pragma unroll
        for (int nt = 0; nt < 4; ++nt) {
            int n  = n0 + wc * 64 + nt * 16 + ln;
            float bias_n = bias[n];
            int hh = n >> 6;
            int d  = n & (DK - 1);
            #pragma unroll
            for (int mt = 0; mt < 4; ++mt)
                #pragma unroll
                for (int r = 0; r < 4; ++r) {
                    int m  = m0 + wr * 64 + mt * 16 + g * 4 + r;
                    int bb = m >> 12;
                    int s  = m & (LSEQ - 1);
                    float val = acc[mt][nt][r] + bias_n;
                    if (mode == 0) val *= QSCALE;
                    out[(size_t)((bb * H + hh) * LSEQ + s) * DK + d] = f2bf(val);
                }
        }
    } else {
        u16* Ts = &smem[0][0][0];
        #pragma unroll
        for (int nt = 0; nt < 4; ++nt) {
            int dl = wc * 64 + nt * 16 + ln;
            float bias_n = bias[n0 + dl];
            #pragma unroll
            for (int mt = 0; mt < 4; ++mt)
                #pragma unroll
                for (int r = 0; r < 4; ++r) {
                    int sl = wr * 64 + mt * 16 + g * 4 + r;
                    Ts[dl * 136 + sl] = f2bf(acc[mt][nt][r] + bias_n);
                }
        }
        __syncthreads();
        int dl   = tid >> 1;
        int half = tid & 1;
        int n  = n0 + dl;
        int hh = n >> 6;
        int d  = n & (DK - 1);
        int bb = m0 >> 12;
        int s0 = (m0 & (LSEQ - 1)) + half * 64;
        u16* dst = out + ((size_t)((bb * H + hh) * DK + d) * LSEQ + s0);
        const u16* srcp = Ts + dl * 136 + half * 64;
        #pragma unroll
        for (int i = 0; i < 8; ++i)
            *(uint4*)(dst + i * 8) = *(const uint4*)(srcp + i * 8);
    }
}

// ---------------------------------------------------------------------------
// Flash attention, transposed-S, q=32/wave, 2-way split-K.
// Round-5 changes:
//  - row-sum l computed by an extra MFMA with an all-ones B fragment
//    (accumulates Sum_k bf16(P)[q][k] into accL, replicated over ln);
//    kills 32 fp32 adds/iter + the epilogue shuffle reduce, and uses the
//    same bf16 P as the PV numerator.
//  - all-ones mask fast path: wave-uniform __all() branch skips the 32
//    cndmasks/iter when this 64-key tile is unmasked (slow path preserved).
// ---------------------------------------------------------------------------
__launch_bounds__(256, 4)
__global__ void flash(const u16* __restrict__ qws, const u16* __restrict__ kws,
                      const u16* __restrict__ vws, const int* __restrict__ mask,
                      u16* __restrict__ Opart, float* __restrict__ lpart)
{
    __shared__ u16 Ks[2][64][72];
    __shared__ u16 Vs[2][64][72];   // [d][pi(key)]

    const int tid   = threadIdx.x;
    const int wave  = tid >> 6;
    const int lane  = tid & 63;
    const int g     = lane >> 4;
    const int ln    = lane & 15;
    const int b     = blockIdx.z;
    const int h     = blockIdx.y;
    const int qblk  = blockIdx.x & 31;
    const int split = blockIdx.x >> 5;
    const int q0    = qblk * 128;
    const int kstart = split * KSPAN;

    const u16* qp = qws + ((size_t)((b * H + h) * LSEQ) + q0 + wave * 32 + ln) * DK;
    const u16* kp = kws + (size_t)(b * H + h) * LSEQ * DK;
    const u16* vp = vws + (size_t)(b * H + h) * DK * LSEQ;
    const int* mp = mask + b * LSEQ;

    bf16x8 qf[2][2];
    qf[0][0] = *(const bf16x8*)(qp + g * 8);
    qf[0][1] = *(const bf16x8*)(qp + 32 + g * 8);
    qf[1][0] = *(const bf16x8*)(qp + 16 * DK + g * 8);
    qf[1][1] = *(const bf16x8*)(qp + 16 * DK + 32 + g * 8);

    // all-ones bf16 B fragment for the l row-sum MFMA
    union OU { unsigned u[4]; bf16x8 v; } onesu;
    onesu.u[0] = onesu.u[1] = onesu.u[2] = onesu.u[3] = 0x3F803F80u;
    const bf16x8 vones = onesu.v;

    f32x4 accO[2][4] = {};
    f32x4 accL[2] = {};

    const int row = tid >> 3;
    const int c   = tid & 7;
    const int vcol0 = ((2 * c) & 3) * 16 + (c >> 1) * 4;

    uint4 kr0, kr1, vr0, vr1;
    kr0 = *(const uint4*)(kp + (size_t)(kstart + row) * DK + c * 8);
    kr1 = *(const uint4*)(kp + (size_t)(kstart + row + 32) * DK + c * 8);
    vr0 = *(const uint4*)(vp + (size_t)row * LSEQ + kstart + c * 8);
    vr1 = *(const uint4*)(vp + (size_t)(row + 32) * LSEQ + kstart + c * 8);
    *(uint4*)&Ks[0][row][c * 8]      = kr0;
    *(uint4*)&Ks[0][row + 32][c * 8] = kr1;
    *(uint2*)&Vs[0][row][vcol0]           = make_uint2(vr0.x, vr0.y);
    *(uint2*)&Vs[0][row][vcol0 + 16]      = make_uint2(vr0.z, vr0.w);
    *(uint2*)&Vs[0][row + 32][vcol0]      = make_uint2(vr1.x, vr1.y);
    *(uint2*)&Vs[0][row + 32][vcol0 + 16] = make_uint2(vr1.z, vr1.w);

    for (int it = 0; it < NIT; ++it) {
        const int cur = it & 1;
        const int k0  = kstart + it * 64;
        __syncthreads();

        if (it < NIT - 1) {
            int kn = k0 + 64;
            kr0 = *(const uint4*)(kp + (size_t)(kn + row) * DK + c * 8);
            kr1 = *(const uint4*)(kp + (size_t)(kn + row + 32) * DK + c * 8);
            vr0 = *(const uint4*)(vp + (size_t)row * LSEQ + kn + c * 8);
            vr1 = *(const uint4*)(vp + (size_t)(row + 32) * LSEQ + kn + c * 8);
        }

        // S^T = K . Q^T for both q-subtiles (K-frags read once)
        f32x4 sc[2][4];
        #pragma unroll
        for (int kb = 0; kb < 4; ++kb) {
            bf16x8 kf0 = *(const bf16x8*)&Ks[cur][kb * 16 + ln][g * 8];
            bf16x8 kf1 = *(const bf16x8*)&Ks[cur][kb * 16 + ln][32 + g * 8];
            #pragma unroll
            for (int j = 0; j < 2; ++j) {
                f32x4 z = {};
                z = mfma32(kf0, qf[j][0], z);
                z = mfma32(kf1, qf[j][1], z);
                sc[j][kb] = z;
            }
        }

        // mask + exp2 (wave-uniform fast path when tile is unmasked)
        int4 mv0 = *(const int4*)(mp + k0 + 0 * 16 + g * 4);
        int4 mv1 = *(const int4*)(mp + k0 + 1 * 16 + g * 4);
        int4 mv2 = *(const int4*)(mp + k0 + 2 * 16 + g * 4);
        int4 mv3 = *(const int4*)(mp + k0 + 3 * 16 + g * 4);
        bool okl = mv0.x && mv0.y && mv0.z && mv0.w &&
                   mv1.x && mv1.y && mv1.z && mv1.w &&
                   mv2.x && mv2.y && mv2.z && mv2.w &&
                   mv3.x && mv3.y && mv3.z && mv3.w;
        if (__all(okl)) {
            #pragma unroll
            for (int kb = 0; kb < 4; ++kb)
                #pragma unroll
                for (int j = 0; j < 2; ++j) {
                    sc[j][kb][0] = fexp2(sc[j][kb][0]);
                    sc[j][kb][1] = fexp2(sc[j][kb][1]);
                    sc[j][kb][2] = fexp2(sc[j][kb][2]);
                    sc[j][kb][3] = fexp2(sc[j][kb][3]);
                }
        } else {
            int4 mvs[4] = {mv0, mv1, mv2, mv3};
            #pragma unroll
            for (int kb = 0; kb < 4; ++kb) {
                int4 mv = mvs[kb];
                #pragma unroll
                for (int j = 0; j < 2; ++j) {
                    sc[j][kb][0] = fexp2(mv.x ? sc[j][kb][0] : -1e9f);
                    sc[j][kb][1] = fexp2(mv.y ? sc[j][kb][1] : -1e9f);
                    sc[j][kb][2] = fexp2(mv.z ? sc[j][kb][2] : -1e9f);
                    sc[j][kb][3] = fexp2(mv.w ? sc[j][kb][3] : -1e9f);
                }
            }
        }

        // pack P fragments (score regs are A-layout under formal-k remap)
        union PU { unsigned u[4]; bf16x8 v; } p01[2], p23[2];
        #pragma unroll
        for (int j = 0; j < 2; ++j) {
            p01[j].u[0] = pkbf(sc[j][0][0], sc[j][0][1]);
            p01[j].u[1] = pkbf(sc[j][0][2], sc[j][0][3]);
            p01[j].u[2] = pkbf(sc[j][1][0], sc[j][1][1]);
            p01[j].u[3] = pkbf(sc[j][1][2], sc[j][1][3]);
            p23[j].u[0] = pkbf(sc[j][2][0], sc[j][2][1]);
            p23[j].u[1] = pkbf(sc[j][2][2], sc[j][2][3]);
            p23[j].u[2] = pkbf(sc[j][3][0], sc[j][3][1]);
            p23[j].u[3] = pkbf(sc[j][3][2], sc[j][3][3]);
        }

        // l row-sums via ones-MFMA; O += P . V
        #pragma unroll
        for (int j = 0; j < 2; ++j) {
            accL[j] = mfma32(p01[j].v, vones, accL[j]);
            accL[j] = mfma32(p23[j].v, vones, accL[j]);
        }
        #pragma unroll
        for (int t = 0; t < 4; ++t) {
            bf16x8 vb01 = *(const bf16x8*)&Vs[cur][t * 16 + ln][g * 16];
            bf16x8 vb23 = *(const bf16x8*)&Vs[cur][t * 16 + ln][g * 16 + 8];
            #pragma unroll
            for (int j = 0; j < 2; ++j) {
                accO[j][t] = mfma32(p01[j].v, vb01, accO[j][t]);
                accO[j][t] = mfma32(p23[j].v, vb23, accO[j][t]);
            }
        }

        if (it < NIT - 1) {
            int nxt = 1 - cur;
            *(uint4*)&Ks[nxt][row][c * 8]      = kr0;
            *(uint4*)&Ks[nxt][row + 32][c * 8] = kr1;
            *(uint2*)&Vs[nxt][row][vcol0]           = make_uint2(vr0.x, vr0.y);
            *(uint2*)&Vs[nxt][row][vcol0 + 16]      = make_uint2(vr0.z, vr0.w);
            *(uint2*)&Vs[nxt][row + 32][vcol0]      = make_uint2(vr1.x, vr1.y);
            *(uint2*)&Vs[nxt][row + 32][vcol0 + 16] = make_uint2(vr1.z, vr1.w);
        }
    }

    // accL[j][r] = l for q-row (g*4+r), replicated over ln.
    const size_t PLANE = (size_t)NB * LSEQ * DM;
    u16* opp = Opart + (size_t)split * PLANE;

    #pragma unroll
    for (int j = 0; j < 2; ++j) {
        if (ln == 0) {
            #pragma unroll
            for (int r = 0; r < 4; ++r)
                lpart[(size_t)split * (NB * H * LSEQ) + ((size_t)(b * H + h) * LSEQ)
                      + q0 + wave * 32 + j * 16 + g * 4 + r] = accL[j][r];
        }
        #pragma unroll
        for (int r = 0; r < 4; ++r) {
            float linv = 1.0f / accL[j][r];
            size_t base = ((size_t)(b * LSEQ) + q0 + wave * 32 + j * 16 + g * 4 + r) * DM + h * DK;
            #pragma unroll
            for (int t = 0; t < 4; ++t)
                opp[base + t * 16 + ln] = f2bf(accO[j][t][r] * linv);
        }
    }
}

// ---------------------------------------------------------------------------
// Output projection, 128x64 tile, with the split-K combine FUSED into the
// A-staging: A = w0*Ohat0 + w1*Ohat1 (weights from lpart, cached+normalized
// in LDS once per block). Replaces the separate reduce_split kernel and its
// ows round-trip.
// ---------------------------------------------------------------------------
__launch_bounds__(256, 2)
__global__ void proj_out(const u16* __restrict__ Opart, const float* __restrict__ lpart,
                         const float* __restrict__ Wo, const float* __restrict__ bo,
                         float* __restrict__ out)
{
    __shared__ u16 As[128][72];
    __shared__ u16 Bs[64][72];
    __shared__ float Wl[2][128][8];   // normalized split weights [split][row][head]

    const size_t PLANE = (size_t)NB * LSEQ * DM;

    const int tid  = threadIdx.x;
    const int wave = tid >> 6;
    const int lane = tid & 63;
    const int g    = lane >> 4;
    const int ln   = lane & 15;

    const int m0 = blockIdx.x * 128;
    const int n0 = blockIdx.y * 64;
    const int bb = m0 >> 12;
    const int qb = m0 & (LSEQ - 1);

    // load + normalize split weights: 128 rows x 8 heads
    #pragma unroll
    for (int i = 0; i < 4; ++i) {
        int idx = tid + 256 * i;          // 0..1023
        int row = idx >> 3;
        int hh  = idx & 7;
        size_t li = ((size_t)(bb * H + hh) * LSEQ) + qb + row;
        float l0 = lpart[li];
        float l1 = lpart[(size_t)NB * H * LSEQ + li];
        float inv = 1.0f / (l0 + l1);
        Wl[0][row][hh] = l0 * inv;
        Wl[1][row][hh] = l1 * inv;
    }
    __syncthreads();

    f32x4 acc[2][4] = {};

    for (int kb = 0; kb < DM; kb += 64) {
        const int hh = kb >> 6;
        #pragma unroll
        for (int i = 0; i < 4; ++i) {
            int idx = tid + 256 * i;
            int row = idx >> 3;
            int col = (idx & 7) * 8;
            float w0 = Wl[0][row][hh];
            float w1 = Wl[1][row][hh];
            uint4 c0 = *(const uint4*)(Opart + (size_t)(m0 + row) * DM + kb + col);
            uint4 c1 = *(const uint4*)(Opart + PLANE + (size_t)(m0 + row) * DM + kb + col);
            float2 a0 = ubf2(c0.x), b0 = ubf2(c1.x);
            float2 a1 = ubf2(c0.y), b1 = ubf2(c1.y);
            float2 a2 = ubf2(c0.z), b2 = ubf2(c1.z);
            float2 a3 = ubf2(c0.w), b3 = ubf2(c1.w);
            uint4 r4;
            r4.x = pkbf(w0 * a0.x + w1 * b0.x, w0 * a0.y + w1 * b0.y);
            r4.y = pkbf(w0 * a1.x + w1 * b1.x, w0 * a1.y + w1 * b1.y);
            r4.z = pkbf(w0 * a2.x + w1 * b2.x, w0 * a2.y + w1 * b2.y);
            r4.w = pkbf(w0 * a3.x + w1 * b3.x, w0 * a3.y + w1 * b3.y);
            *(uint4*)&As[row][col] = r4;
        }
        #pragma unroll
        for (int i = 0; i < 4; ++i) {
            int idx = tid + 256 * i;
            int row = idx >> 4;
            int col = (idx & 15) * 4;
            float4 w = *(const float4*)(Wo + (size_t)(n0 + row) * DM + kb + col);
            *(ushort4*)&Bs[row][col] = cvt4(w);
        }
        __syncthreads();

        bf16x8 af[2][2], bf[4][2];
        #pragma unroll
        for (int mt = 0; mt < 2; ++mt) {
            af[mt][0] = *(const bf16x8*)&As[wave * 32 + mt * 16 + ln][g * 8];
            af[mt][1] = *(const bf16x8*)&As[wave * 32 + mt * 16 + ln][32 + g * 8];
        }
        #pragma unroll
        for (int nt = 0; nt < 4; ++nt) {
            bf[nt][0] = *(const bf16x8*)&Bs[nt * 16 + ln][g * 8];
            bf[nt][1] = *(const bf16x8*)&Bs[nt * 16 + ln][32 + g * 8];
        }
        #pragma unroll
        for (int mt = 0; mt < 2; ++mt)
            #pragma unroll
            for (int nt = 0; nt < 4; ++nt) {
                acc[mt][nt] = mfma32(af[mt][0], bf[nt][0], acc[mt][nt]);
                acc[mt][nt] = mfma32(af[mt][1], bf[nt][1], acc[mt][nt]);
            }
        __syncthreads();
    }

    #pragma unroll
    for (int nt = 0; nt < 4; ++nt) {
        int n = n0 + nt * 16 + ln;
        float bias_n = bo[n];
        #pragma unroll
        for (int mt = 0; mt < 2; ++mt)
            #pragma unroll
            for (int r = 0; r < 4; ++r) {
                int m = m0 + wave * 32 + mt * 16 + g * 4 + r;
                out[(size_t)m * DM + n] = acc[mt][nt][r] + bias_n;
            }
    }
}

// ---------------------------------------------------------------------------
extern "C" void kernel_launch(void* const* d_in, const int* in_sizes, int n_in,
                              void* d_out, int out_size, void* d_ws, size_t ws_size,
                              hipStream_t stream) {
    (void)in_sizes; (void)n_in; (void)out_size; (void)ws_size;

    const float* query = (const float*)d_in[0];
    const float* key   = (const float*)d_in[1];
    const float* value = (const float*)d_in[2];
    const int*   mask  = (const int*)d_in[3];
    const float* Wq = (const float*)d_in[4];
    const float* bq = (const float*)d_in[5];
    const float* Wk = (const float*)d_in[6];
    const float* bk = (const float*)d_in[7];
    const float* Wv = (const float*)d_in[8];
    const float* bv = (const float*)d_in[9];
    const float* Wo = (const float*)d_in[10];
    const float* bo = (const float*)d_in[11];
    float* out = (float*)d_out;

    // ws layout (u16 elems): qws | kws | vws | Opart(2 planes) | lpart(f32)
    const size_t PLANE = (size_t)NB * H * LSEQ * DK;   // 4,194,304 (== NB*LSEQ*DM)
    u16* qws   = (u16*)d_ws;
    u16* kws   = qws + PLANE;
    u16* vws   = kws + PLANE;
    u16* Opart = vws + PLANE;                               // NSPLIT * PLANE u16
    float* lpart = (float*)(Opart + (size_t)NSPLIT * PLANE); // NSPLIT*NB*H*LSEQ f32

    dim3 blk(256);
    proj_qkv<<<dim3(64, 4, 3), blk, 0, stream>>>(query, key, value, Wq, Wk, Wv,
                                                 bq, bk, bv, qws, kws, vws);
    flash<<<dim3(32 * NSPLIT, H, NB), blk, 0, stream>>>(qws, kws, vws, mask, Opart, lpart);
    proj_out<<<dim3(64, 8, 1), blk, 0, stream>>>(Opart, lpart, Wo, bo, out);
}

// Round 6
// 266.944 us; speedup vs baseline: 1.4919x; 1.4919x over previous
//
#include <hip/hip_runtime.h>
#include <hip/hip_bf16.h>

#define H 8
#define DM 512
#define DK 64
#define LSEQ 4096
#define NB 2
#define NSPLIT 2
#define KSPAN (LSEQ / NSPLIT)   // keys per split = 2048
#define NIT (KSPAN / 64)        // 32 k-tiles per block

// 0.125 (1/sqrt(DK)) * log2(e): folded into Q so softmax uses exp2 directly
#define QSCALE 0.18033688011112042f

// ws element counts
#define PLANE_EL   ((size_t)NB * H * LSEQ * DK)          // 4,194,304 u16
#define LPART_EL   ((size_t)NSPLIT * NB * H * LSEQ)      // 131,072 f32
#define XSEG_EL    ((size_t)NB * LSEQ * DM)              // 4,194,304 per X tensor
#define WSEG_EL    ((size_t)DM * DM)                     // 262,144 per W
#define XW_EL      (3 * XSEG_EL + 4 * WSEG_EL)           // 13,631,488
#define WS_NEEDED  ((5 * PLANE_EL + XW_EL) * 2 + LPART_EL * 4)   // 69,730,304 B

typedef float f32x4 __attribute__((ext_vector_type(4)));
typedef __bf16 bf16x8 __attribute__((ext_vector_type(8)));
typedef __bf16 bf16x2 __attribute__((ext_vector_type(2)));
typedef unsigned short u16;

__device__ __forceinline__ u16 f2bf(float f) {
    union { float f; unsigned u; } v{f};
    return (u16)((v.u + 0x8000u) >> 16);
}

__device__ __forceinline__ unsigned pkbf(float a, float b) {
#if __has_builtin(__builtin_amdgcn_cvt_pk_bf16_f32)
    union { bf16x2 v; unsigned u; } x;
    x.v = __builtin_amdgcn_cvt_pk_bf16_f32(a, b);
    return x.u;
#else
    union { float f; unsigned u; } x{a}, y{b};
    return ((x.u + 0x8000u) >> 16) | ((y.u + 0x8000u) & 0xffff0000u);
#endif
}

__device__ __forceinline__ ushort4 cvt4(float4 a) {
    union { ushort4 s; uint2 u; } o;
    o.u.x = pkbf(a.x, a.y);
    o.u.y = pkbf(a.z, a.w);
    return o.s;
}

__device__ __forceinline__ float2 ubf2(unsigned u) {
    union { float f; unsigned v; } a, b;
    a.v = u << 16;
    b.v = u & 0xffff0000u;
    return make_float2(a.f, b.f);
}

__device__ __forceinline__ float fexp2(float x) {
#if __has_builtin(__builtin_amdgcn_exp2f)
    return __builtin_amdgcn_exp2f(x);
#else
    return exp2f(x);
#endif
}

__device__ __forceinline__ f32x4 mfma32(bf16x8 a, bf16x8 b, f32x4 c) {
    return __builtin_amdgcn_mfma_f32_16x16x32_bf16(a, b, c, 0, 0, 0);
}

// ---------------------------------------------------------------------------
// Prepass: convert query/key/value + Wq/Wk/Wv/Wo fp32 -> bf16 into XWbuf
// (contiguous: xq|xk|xv|wq|wk|wv|wo). One float4 chunk per thread.
// ---------------------------------------------------------------------------
__launch_bounds__(256)
__global__ void cvt_inputs(const float* __restrict__ xq, const float* __restrict__ xk,
                           const float* __restrict__ xv,
                           const float* __restrict__ wq, const float* __restrict__ wk,
                           const float* __restrict__ wv, const float* __restrict__ wo,
                           u16* __restrict__ XWbuf)
{
    size_t f = ((size_t)blockIdx.x * 256 + threadIdx.x) * 4;   // flat element idx
    if (f >= XW_EL) return;
    const float* src;
    size_t local;
    if (f < 3 * XSEG_EL) {
        int seg = (int)(f >> 22);            // XSEG_EL = 2^22
        local   = f & (XSEG_EL - 1);
        src = (seg == 0) ? xq : (seg == 1) ? xk : xv;
    } else {
        size_t w = f - 3 * XSEG_EL;
        int seg = (int)(w >> 18);            // WSEG_EL = 2^18
        local   = w & (WSEG_EL - 1);
        src = (seg == 0) ? wq : (seg == 1) ? wk : (seg == 2) ? wv : wo;
    }
    float4 v = *(const float4*)(src + local);
    *(ushort4*)(XWbuf + f) = cvt4(v);
}

// ---------------------------------------------------------------------------
// QKV projection, 128x128 tile: out = X @ W^T + b -> bf16.
// useBf: stage from pre-converted bf16 (uint4, no cvt in loop); else fp32+cvt.
// mode 0 (Q): scaled by QSCALE, (b,h,s,d); 1 (K): (b,h,s,d); 2 (V): (b,h,d,s)
// via LDS transpose.
// ---------------------------------------------------------------------------
__launch_bounds__(256, 2)
__global__ void proj_qkv(const float* __restrict__ Xq, const float* __restrict__ Xk,
                         const float* __restrict__ Xv,
                         const float* __restrict__ Wq, const float* __restrict__ Wk,
                         const float* __restrict__ Wv,
                         const float* __restrict__ bq, const float* __restrict__ bk,
                         const float* __restrict__ bv,
                         const u16* __restrict__ XWbuf, int useBf,
                         u16* __restrict__ qo, u16* __restrict__ ko, u16* __restrict__ vo)
{
    const int mode = blockIdx.z;
    const float* X    = (mode == 0) ? Xq : (mode == 1) ? Xk : Xv;
    const float* W    = (mode == 0) ? Wq : (mode == 1) ? Wk : Wv;
    const float* bias = (mode == 0) ? bq : (mode == 1) ? bk : bv;
    u16* out          = (mode == 0) ? qo : (mode == 1) ? ko : vo;
    const u16* Xb = XWbuf + (size_t)mode * XSEG_EL;
    const u16* Wb = XWbuf + 3 * XSEG_EL + (size_t)mode * WSEG_EL;

    __shared__ __align__(16) u16 smem[2][128][72];
    auto As = smem[0];
    auto Bs = smem[1];

    const int tid  = threadIdx.x;
    const int wave = tid >> 6;
    const int lane = tid & 63;
    const int g    = lane >> 4;
    const int ln   = lane & 15;
    const int wr   = wave >> 1;
    const int wc   = wave & 1;

    const int m0 = blockIdx.x * 128;
    const int n0 = blockIdx.y * 128;

    f32x4 acc[4][4] = {};

    for (int kb = 0; kb < DM; kb += 64) {
        if (useBf) {
            #pragma unroll
            for (int i = 0; i < 4; ++i) {
                int idx = tid + 256 * i;          // 1024 uint4 chunks each
                int row = idx >> 3;
                int col = (idx & 7) * 8;
                *(uint4*)&As[row][col] = *(const uint4*)(Xb + (size_t)(m0 + row) * DM + kb + col);
                *(uint4*)&Bs[row][col] = *(const uint4*)(Wb + (size_t)(n0 + row) * DM + kb + col);
            }
        } else {
            #pragma unroll
            for (int i = 0; i < 8; ++i) {
                int idx = tid + 256 * i;
                int row = idx >> 4;
                int col = (idx & 15) * 4;
                float4 a = *(const float4*)(X + (size_t)(m0 + row) * DM + kb + col);
                *(ushort4*)&As[row][col] = cvt4(a);
                float4 w = *(const float4*)(W + (size_t)(n0 + row) * DM + kb + col);
                *(ushort4*)&Bs[row][col] = cvt4(w);
            }
        }
        __syncthreads();

        bf16x8 af[4][2], bf[4][2];
        #pragma unroll
        for (int t = 0; t < 4; ++t) {
            af[t][0] = *(const bf16x8*)&As[wr * 64 + t * 16 + ln][g * 8];
            af[t][1] = *(const bf16x8*)&As[wr * 64 + t * 16 + ln][32 + g * 8];
            bf[t][0] = *(const bf16x8*)&Bs[wc * 64 + t * 16 + ln][g * 8];
            bf[t][1] = *(const bf16x8*)&Bs[wc * 64 + t * 16 + ln][32 + g * 8];
        }
        #pragma unroll
        for (int mt = 0; mt < 4; ++mt)
            #pragma unroll
            for (int nt = 0; nt < 4; ++nt) {
                acc[mt][nt] = mfma32(af[mt][0], bf[nt][0], acc[mt][nt]);
                acc[mt][nt] = mfma32(af[mt][1], bf[nt][1], acc[mt][nt]);
            }
        __syncthreads();
    }

    if (mode != 2) {
        #pragma unroll
        for (int nt = 0; nt < 4; ++nt) {
            int n  = n0 + wc * 64 + nt * 16 + ln;
            float bias_n = bias[n];
            int hh = n >> 6;
            int d  = n & (DK - 1);
            #pragma unroll
            for (int mt = 0; mt < 4; ++mt)
                #pragma unroll
                for (int r = 0; r < 4; ++r) {
                    int m  = m0 + wr * 64 + mt * 16 + g * 4 + r;
                    int bb = m >> 12;
                    int s  = m & (LSEQ - 1);
                    float val = acc[mt][nt][r] + bias_n;
                    if (mode == 0) val *= QSCALE;
                    out[(size_t)((bb * H + hh) * LSEQ + s) * DK + d] = f2bf(val);
                }
        }
    } else {
        u16* Ts = &smem[0][0][0];
        #pragma unroll
        for (int nt = 0; nt < 4; ++nt) {
            int dl = wc * 64 + nt * 16 + ln;
            float bias_n = bias[n0 + dl];
            #pragma unroll
            for (int mt = 0; mt < 4; ++mt)
                #pragma unroll
                for (int r = 0; r < 4; ++r) {
                    int sl = wr * 64 + mt * 16 + g * 4 + r;
                    Ts[dl * 136 + sl] = f2bf(acc[mt][nt][r] + bias_n);
                }
        }
        __syncthreads();
        int dl   = tid >> 1;
        int half = tid & 1;
        int n  = n0 + dl;
        int hh = n >> 6;
        int d  = n & (DK - 1);
        int bb = m0 >> 12;
        int s0 = (m0 & (LSEQ - 1)) + half * 64;
        u16* dst = out + ((size_t)((bb * H + hh) * DK + d) * LSEQ + s0);
        const u16* srcp = Ts + dl * 136 + half * 64;
        #pragma unroll
        for (int i = 0; i < 8; ++i)
            *(uint4*)(dst + i * 8) = *(const uint4*)(srcp + i * 8);
    }
}

// ---------------------------------------------------------------------------
// Flash attention, transposed-S, q=32/wave, 2-way split-K.
// Softmax block uses the ROUND-4 structure (per-kb mask int4, consumed
// immediately) — the round-5 mask prefetch/fast-path held 4x int4 + okl live
// across the 32-reg score window and SPILLED (WRITE_SIZE 17->538 MB).
// Keeps the ones-MFMA row-sum accL (no per-lane adds, no epilogue shuffles).
// ---------------------------------------------------------------------------
__launch_bounds__(256, 4)
__global__ void flash(const u16* __restrict__ qws, const u16* __restrict__ kws,
                      const u16* __restrict__ vws, const int* __restrict__ mask,
                      u16* __restrict__ Opart, float* __restrict__ lpart)
{
    __shared__ u16 Ks[2][64][72];
    __shared__ u16 Vs[2][64][72];   // [d][pi(key)]

    const int tid   = threadIdx.x;
    const int wave  = tid >> 6;
    const int lane  = tid & 63;
    const int g     = lane >> 4;
    const int ln    = lane & 15;
    const int b     = blockIdx.z;
    const int h     = blockIdx.y;
    const int qblk  = blockIdx.x & 31;
    const int split = blockIdx.x >> 5;
    const int q0    = qblk * 128;
    const int kstart = split * KSPAN;

    const u16* qp = qws + ((size_t)((b * H + h) * LSEQ) + q0 + wave * 32 + ln) * DK;
    const u16* kp = kws + (size_t)(b * H + h) * LSEQ * DK;
    const u16* vp = vws + (size_t)(b * H + h) * DK * LSEQ;
    const int* mp = mask + b * LSEQ;

    bf16x8 qf[2][2];
    qf[0][0] = *(const bf16x8*)(qp + g * 8);
    qf[0][1] = *(const bf16x8*)(qp + 32 + g * 8);
    qf[1][0] = *(const bf16x8*)(qp + 16 * DK + g * 8);
    qf[1][1] = *(const bf16x8*)(qp + 16 * DK + 32 + g * 8);

    union OU { unsigned u[4]; bf16x8 v; } onesu;
    onesu.u[0] = onesu.u[1] = onesu.u[2] = onesu.u[3] = 0x3F803F80u;
    const bf16x8 vones = onesu.v;

    f32x4 accO[2][4] = {};
    f32x4 accL[2] = {};

    const int row = tid >> 3;
    const int c   = tid & 7;
    const int vcol0 = ((2 * c) & 3) * 16 + (c >> 1) * 4;

    uint4 kr0, kr1, vr0, vr1;
    kr0 = *(const uint4*)(kp + (size_t)(kstart + row) * DK + c * 8);
    kr1 = *(const uint4*)(kp + (size_t)(kstart + row + 32) * DK + c * 8);
    vr0 = *(const uint4*)(vp + (size_t)row * LSEQ + kstart + c * 8);
    vr1 = *(const uint4*)(vp + (size_t)(row + 32) * LSEQ + kstart + c * 8);
    *(uint4*)&Ks[0][row][c * 8]      = kr0;
    *(uint4*)&Ks[0][row + 32][c * 8] = kr1;
    *(uint2*)&Vs[0][row][vcol0]           = make_uint2(vr0.x, vr0.y);
    *(uint2*)&Vs[0][row][vcol0 + 16]      = make_uint2(vr0.z, vr0.w);
    *(uint2*)&Vs[0][row + 32][vcol0]      = make_uint2(vr1.x, vr1.y);
    *(uint2*)&Vs[0][row + 32][vcol0 + 16] = make_uint2(vr1.z, vr1.w);

    for (int it = 0; it < NIT; ++it) {
        const int cur = it & 1;
        const int k0  = kstart + it * 64;
        __syncthreads();

        if (it < NIT - 1) {
            int kn = k0 + 64;
            kr0 = *(const uint4*)(kp + (size_t)(kn + row) * DK + c * 8);
            kr1 = *(const uint4*)(kp + (size_t)(kn + row + 32) * DK + c * 8);
            vr0 = *(const uint4*)(vp + (size_t)row * LSEQ + kn + c * 8);
            vr1 = *(const uint4*)(vp + (size_t)(row + 32) * LSEQ + kn + c * 8);
        }

        // S^T = K . Q^T for both q-subtiles (K-frags read once)
        f32x4 sc[2][4];
        #pragma unroll
        for (int kb = 0; kb < 4; ++kb) {
            bf16x8 kf0 = *(const bf16x8*)&Ks[cur][kb * 16 + ln][g * 8];
            bf16x8 kf1 = *(const bf16x8*)&Ks[cur][kb * 16 + ln][32 + g * 8];
            #pragma unroll
            for (int j = 0; j < 2; ++j) {
                f32x4 z = {};
                z = mfma32(kf0, qf[j][0], z);
                z = mfma32(kf1, qf[j][1], z);
                sc[j][kb] = z;
            }
        }

        // mask + exp2 (round-4 structure: one int4 live at a time)
        #pragma unroll
        for (int kb = 0; kb < 4; ++kb) {
            int4 mv = *(const int4*)(mp + k0 + kb * 16 + g * 4);
            #pragma unroll
            for (int j = 0; j < 2; ++j) {
                sc[j][kb][0] = fexp2(mv.x ? sc[j][kb][0] : -1e9f);
                sc[j][kb][1] = fexp2(mv.y ? sc[j][kb][1] : -1e9f);
                sc[j][kb][2] = fexp2(mv.z ? sc[j][kb][2] : -1e9f);
                sc[j][kb][3] = fexp2(mv.w ? sc[j][kb][3] : -1e9f);
            }
        }

        // pack P fragments (score regs are A-layout under formal-k remap)
        union PU { unsigned u[4]; bf16x8 v; } p01[2], p23[2];
        #pragma unroll
        for (int j = 0; j < 2; ++j) {
            p01[j].u[0] = pkbf(sc[j][0][0], sc[j][0][1]);
            p01[j].u[1] = pkbf(sc[j][0][2], sc[j][0][3]);
            p01[j].u[2] = pkbf(sc[j][1][0], sc[j][1][1]);
            p01[j].u[3] = pkbf(sc[j][1][2], sc[j][1][3]);
            p23[j].u[0] = pkbf(sc[j][2][0], sc[j][2][1]);
            p23[j].u[1] = pkbf(sc[j][2][2], sc[j][2][3]);
            p23[j].u[2] = pkbf(sc[j][3][0], sc[j][3][1]);
            p23[j].u[3] = pkbf(sc[j][3][2], sc[j][3][3]);
        }

        // l row-sums via ones-MFMA; O += P . V
        #pragma unroll
        for (int j = 0; j < 2; ++j) {
            accL[j] = mfma32(p01[j].v, vones, accL[j]);
            accL[j] = mfma32(p23[j].v, vones, accL[j]);
        }
        #pragma unroll
        for (int t = 0; t < 4; ++t) {
            bf16x8 vb01 = *(const bf16x8*)&Vs[cur][t * 16 + ln][g * 16];
            bf16x8 vb23 = *(const bf16x8*)&Vs[cur][t * 16 + ln][g * 16 + 8];
            #pragma unroll
            for (int j = 0; j < 2; ++j) {
                accO[j][t] = mfma32(p01[j].v, vb01, accO[j][t]);
                accO[j][t] = mfma32(p23[j].v, vb23, accO[j][t]);
            }
        }

        if (it < NIT - 1) {
            int nxt = 1 - cur;
            *(uint4*)&Ks[nxt][row][c * 8]      = kr0;
            *(uint4*)&Ks[nxt][row + 32][c * 8] = kr1;
            *(uint2*)&Vs[nxt][row][vcol0]           = make_uint2(vr0.x, vr0.y);
            *(uint2*)&Vs[nxt][row][vcol0 + 16]      = make_uint2(vr0.z, vr0.w);
            *(uint2*)&Vs[nxt][row + 32][vcol0]      = make_uint2(vr1.x, vr1.y);
            *(uint2*)&Vs[nxt][row + 32][vcol0 + 16] = make_uint2(vr1.z, vr1.w);
        }
    }

    // accL[j][r] = l for q-row (g*4+r), replicated over ln.
    const size_t PLANE = (size_t)NB * LSEQ * DM;
    u16* opp = Opart + (size_t)split * PLANE;

    #pragma unroll
    for (int j = 0; j < 2; ++j) {
        if (ln == 0) {
            #pragma unroll
            for (int r = 0; r < 4; ++r)
                lpart[(size_t)split * (NB * H * LSEQ) + ((size_t)(b * H + h) * LSEQ)
                      + q0 + wave * 32 + j * 16 + g * 4 + r] = accL[j][r];
        }
        #pragma unroll
        for (int r = 0; r < 4; ++r) {
            float linv = 1.0f / accL[j][r];
            size_t base = ((size_t)(b * LSEQ) + q0 + wave * 32 + j * 16 + g * 4 + r) * DM + h * DK;
            #pragma unroll
            for (int t = 0; t < 4; ++t)
                opp[base + t * 16 + ln] = f2bf(accO[j][t][r] * linv);
        }
    }
}

// ---------------------------------------------------------------------------
// Output projection, 128x64 tile, split-K combine fused into A-staging.
// B staged from pre-converted Wo bf16 when useBf.
// ---------------------------------------------------------------------------
__launch_bounds__(256, 2)
__global__ void proj_out(const u16* __restrict__ Opart, const float* __restrict__ lpart,
                         const float* __restrict__ Wo, const u16* __restrict__ Wob,
                         int useBf, const float* __restrict__ bo,
                         float* __restrict__ out)
{
    __shared__ u16 As[128][72];
    __shared__ u16 Bs[64][72];
    __shared__ float Wl[2][128][8];   // normalized split weights [split][row][head]

    const size_t PLANE = (size_t)NB * LSEQ * DM;

    const int tid  = threadIdx.x;
    const int wave = tid >> 6;
    const int lane = tid & 63;
    const int g    = lane >> 4;
    const int ln   = lane & 15;

    const int m0 = blockIdx.x * 128;
    const int n0 = blockIdx.y * 64;
    const int bb = m0 >> 12;
    const int qb = m0 & (LSEQ - 1);

    #pragma unroll
    for (int i = 0; i < 4; ++i) {
        int idx = tid + 256 * i;
        int row = idx >> 3;
        int hh  = idx & 7;
        size_t li = ((size_t)(bb * H + hh) * LSEQ) + qb + row;
        float l0 = lpart[li];
        float l1 = lpart[(size_t)NB * H * LSEQ + li];
        float inv = 1.0f / (l0 + l1);
        Wl[0][row][hh] = l0 * inv;
        Wl[1][row][hh] = l1 * inv;
    }
    __syncthreads();

    f32x4 acc[2][4] = {};

    for (int kb = 0; kb < DM; kb += 64) {
        const int hh = kb >> 6;
        #pragma unroll
        for (int i = 0; i < 4; ++i) {
            int idx = tid + 256 * i;
            int row = idx >> 3;
            int col = (idx & 7) * 8;
            float w0 = Wl[0][row][hh];
            float w1 = Wl[1][row][hh];
            uint4 c0 = *(const uint4*)(Opart + (size_t)(m0 + row) * DM + kb + col);
            uint4 c1 = *(const uint4*)(Opart + PLANE + (size_t)(m0 + row) * DM + kb + col);
            float2 a0 = ubf2(c0.x), b0 = ubf2(c1.x);
            float2 a1 = ubf2(c0.y), b1 = ubf2(c1.y);
            float2 a2 = ubf2(c0.z), b2 = ubf2(c1.z);
            float2 a3 = ubf2(c0.w), b3 = ubf2(c1.w);
            uint4 r4;
            r4.x = pkbf(w0 * a0.x + w1 * b0.x, w0 * a0.y + w1 * b0.y);
            r4.y = pkbf(w0 * a1.x + w1 * b1.x, w0 * a1.y + w1 * b1.y);
            r4.z = pkbf(w0 * a2.x + w1 * b2.x, w0 * a2.y + w1 * b2.y);
            r4.w = pkbf(w0 * a3.x + w1 * b3.x, w0 * a3.y + w1 * b3.y);
            *(uint4*)&As[row][col] = r4;
        }
        if (useBf) {
            #pragma unroll
            for (int i = 0; i < 2; ++i) {
                int idx = tid + 256 * i;          // 512 uint4 chunks
                int row = idx >> 3;
                int col = (idx & 7) * 8;
                *(uint4*)&Bs[row][col] = *(const uint4*)(Wob + (size_t)(n0 + row) * DM + kb + col);
            }
        } else {
            #pragma unroll
            for (int i = 0; i < 4; ++i) {
                int idx = tid + 256 * i;
                int row = idx >> 4;
                int col = (idx & 15) * 4;
                float4 w = *(const float4*)(Wo + (size_t)(n0 + row) * DM + kb + col);
                *(ushort4*)&Bs[row][col] = cvt4(w);
            }
        }
        __syncthreads();

        bf16x8 af[2][2], bf[4][2];
        #pragma unroll
        for (int mt = 0; mt < 2; ++mt) {
            af[mt][0] = *(const bf16x8*)&As[wave * 32 + mt * 16 + ln][g * 8];
            af[mt][1] = *(const bf16x8*)&As[wave * 32 + mt * 16 + ln][32 + g * 8];
        }
        #pragma unroll
        for (int nt = 0; nt < 4; ++nt) {
            bf[nt][0] = *(const bf16x8*)&Bs[nt * 16 + ln][g * 8];
            bf[nt][1] = *(const bf16x8*)&Bs[nt * 16 + ln][32 + g * 8];
        }
        #pragma unroll
        for (int mt = 0; mt < 2; ++mt)
            #pragma unroll
            for (int nt = 0; nt < 4; ++nt) {
                acc[mt][nt] = mfma32(af[mt][0], bf[nt][0], acc[mt][nt]);
                acc[mt][nt] = mfma32(af[mt][1], bf[nt][1], acc[mt][nt]);
            }
        __syncthreads();
    }

    #pragma unroll
    for (int nt = 0; nt < 4; ++nt) {
        int n = n0 + nt * 16 + ln;
        float bias_n = bo[n];
        #pragma unroll
        for (int mt = 0; mt < 2; ++mt)
            #pragma unroll
            for (int r = 0; r < 4; ++r) {
                int m = m0 + wave * 32 + mt * 16 + g * 4 + r;
                out[(size_t)m * DM + n] = acc[mt][nt][r] + bias_n;
            }
    }
}

// ---------------------------------------------------------------------------
extern "C" void kernel_launch(void* const* d_in, const int* in_sizes, int n_in,
                              void* d_out, int out_size, void* d_ws, size_t ws_size,
                              hipStream_t stream) {
    (void)in_sizes; (void)n_in; (void)out_size;

    const float* query = (const float*)d_in[0];
    const float* key   = (const float*)d_in[1];
    const float* value = (const float*)d_in[2];
    const int*   mask  = (const int*)d_in[3];
    const float* Wq = (const float*)d_in[4];
    const float* bq = (const float*)d_in[5];
    const float* Wk = (const float*)d_in[6];
    const float* bk = (const float*)d_in[7];
    const float* Wv = (const float*)d_in[8];
    const float* bv = (const float*)d_in[9];
    const float* Wo = (const float*)d_in[10];
    const float* bo = (const float*)d_in[11];
    float* out = (float*)d_out;

    // ws layout (u16 elems): qws | kws | vws | Opart(2) | lpart(f32) | XWbuf
    u16* qws   = (u16*)d_ws;
    u16* kws   = qws + PLANE_EL;
    u16* vws   = kws + PLANE_EL;
    u16* Opart = vws + PLANE_EL;
    float* lpart = (float*)(Opart + (size_t)NSPLIT * PLANE_EL);
    u16* XWbuf = (u16*)(lpart + LPART_EL);
    u16* Wob   = XWbuf + 3 * XSEG_EL + 3 * WSEG_EL;

    const int useBf = (ws_size >= (size_t)WS_NEEDED) ? 1 : 0;

    dim3 blk(256);
    if (useBf) {
        int nblk = (int)((XW_EL / 4 + 255) / 256);
        cvt_inputs<<<dim3(nblk), blk, 0, stream>>>(query, key, value, Wq, Wk, Wv, Wo, XWbuf);
    }
    proj_qkv<<<dim3(64, 4, 3), blk, 0, stream>>>(query, key, value, Wq, Wk, Wv,
                                                 bq, bk, bv, XWbuf, useBf, qws, kws, vws);
    flash<<<dim3(32 * NSPLIT, H, NB), blk, 0, stream>>>(qws, kws, vws, mask, Opart, lpart);
    proj_out<<<dim3(64, 8, 1), blk, 0, stream>>>(Opart, lpart, Wo, Wob, useBf, bo, out);
}